// Round 3
// baseline (31518.060 us; speedup 1.0000x reference)
//
#include <hip/hip_runtime.h>
#include <cstdint>
#include <cstddef>

// ============================================================================
// QuantGRU on MI355X — round 5
//
// vs rounds 2-4 (13.8-15 ms, floored at ~2 us per cross-WG reduction x 6
// serial reductions/step; sc0/L2-local exchange proved a dead end in r4):
//  * SINGLE-WORKGROUP recurrence: 1024 threads, 16 waves, one CU computes
//    the full 64x256 domain.  All 6 per-step global maxes become block-local
//    (shuffle + LDS atomicMax + __syncthreads, ~0.1 us each).  Zero cross-WG
//    communication, zero protocol risk.
//  * Fits 16-wave occupancy (<=128 VGPR) by re-quantizing inter-stage state
//    into packed int8 CODES (4/dword): every quantized value is s*(float)k
//    with k integral in [-127,127], so storing k and recomputing s*(float)k
//    is bit-identical to keeping the float.  R fragments are reloaded from
//    L2 per kc per step instead of held resident.
//  * All float ops replicate the proven round-2 op order exactly
//    (absmax margin is thin: expect exactly 0.06115723).
// ============================================================================

typedef int   v4i __attribute__((ext_vector_type(4)));
typedef float v4f __attribute__((ext_vector_type(4)));

#define T_STEPS 1024
#define OUT_MAIN_FLOATS (1024*64*256)          // 16,777,216
#define WXQ_DOUT_OFF 16842752                  // out_bytes(67,174,400) - 50,331,648

__device__ __forceinline__ float clamp128(float x) {
  return fminf(fmaxf(x, -128.0f), 127.0f);
}
__device__ __forceinline__ int permj(int j) {           // haste row -> pt row
  return j < 256 ? j + 256 : (j < 512 ? j - 256 : j);
}
__device__ __forceinline__ float sigmoidf_(float x) {
  return __fdividef(1.0f, 1.0f + __expf(-x));
}
__device__ __forceinline__ float tanhf_(float x) {
  float e = __expf(-2.0f * fabsf(x));
  float t = __fdividef(1.0f - e, 1.0f + e);
  return copysignf(t, x);
}
// monotone uint key for signed float max
__device__ __forceinline__ unsigned skey(float x) {
  unsigned u = __float_as_uint(x);
  return (u & 0x80000000u) ? ~u : (u | 0x80000000u);
}
__device__ __forceinline__ float sdec(unsigned k) {
  unsigned u = (k & 0x80000000u) ? (k ^ 0x80000000u) : ~k;
  return __uint_as_float(u);
}
__device__ __forceinline__ float wave_amax(float v) {
  #pragma unroll
  for (int m = 1; m <= 32; m <<= 1) v = fmaxf(v, __shfl_xor(v, m, 64));
  return v;
}
__device__ __forceinline__ float sgnb(int dw, int rg) {   // signed byte -> float
  return (float)((signed char)(dw >> (rg * 8)));
}

#define MFMA_I8(a, b, c) __builtin_amdgcn_mfma_i32_16x16x64_i8(a, b, c, 0, 0, 0)

// ---------------- absmax over a float tensor (n4 = n/4) ----------------
__global__ void k_absmax(const float* __restrict__ p, int n4, unsigned* slot) {
  int i = blockIdx.x * blockDim.x + threadIdx.x;
  int stride = gridDim.x * blockDim.x;
  const v4f* p4 = (const v4f*)p;
  float m = 0.0f;
  for (; i < n4; i += stride) {
    v4f v = p4[i];
    m = fmaxf(m, fmaxf(fmaxf(fabsf(v[0]), fabsf(v[1])),
                       fmaxf(fabsf(v[2]), fabsf(v[3]))));
  }
  m = wave_amax(m);
  if ((threadIdx.x & 63) == 0) atomicMax(slot, __float_as_uint(m));
}

// ---------------- 768x256 weight -> int8 MFMA B-fragments ----------------
__global__ void k_frag(const float* __restrict__ src,
                       const unsigned* __restrict__ slots, int slot_idx,
                       signed char* __restrict__ dst) {
  int id = blockIdx.x * 256 + threadIdx.x;   // 0..49151
  float s = fmaxf(__uint_as_float(slots[slot_idx]) / 127.0f, 1e-8f);
  int bq   = id & 3;
  int lane = (id >> 2) & 63;
  int kc   = (id >> 8) & 3;
  int ct   = id >> 10;
  int n = ct * 16 + (lane & 15);
  int k = kc * 64 + (lane >> 4) * 16 + bq * 4;
  const float* p = src + permj(n) * 256 + k;
  int b0 = ((int)clamp128(rintf(p[0] / s))) & 255;
  int b1 = ((int)clamp128(rintf(p[1] / s))) & 255;
  int b2 = ((int)clamp128(rintf(p[2] / s))) & 255;
  int b3 = ((int)clamp128(rintf(p[3] / s))) & 255;
  ((int*)dst)[id] = b0 | (b1 << 8) | (b2 << 16) | (b3 << 24);
}

// ---------------- biases: reorder + fake-quant (dequantized fp32) ----------
__global__ void k_bias(const float* __restrict__ bih, const float* __restrict__ bhh,
                       const unsigned* __restrict__ slots, float* __restrict__ bqo) {
  int j = threadIdx.x;               // 0..767
  float s_bx = fmaxf(__uint_as_float(slots[3]) / 127.0f, 1e-8f);
  float s_br = fmaxf(__uint_as_float(slots[4]) / 127.0f, 1e-8f);
  int pr = permj(j);
  bqo[j]       = s_bx * clamp128(rintf(bih[pr] / s_bx));
  bqo[768 + j] = s_br * clamp128(rintf(bhh[pr] / s_br));
}

// ---------------- quantize x -> int8 ----------------
__global__ void k_xq(const float* __restrict__ x, const unsigned* __restrict__ slots,
                     signed char* __restrict__ xq8, int n4) {
  int i = blockIdx.x * blockDim.x + threadIdx.x;
  if (i >= n4) return;
  float s_x = fmaxf(__uint_as_float(slots[0]) / 127.0f, 1e-8f);
  v4f v = ((const v4f*)x)[i];
  int b0 = ((int)clamp128(rintf(v[0] / s_x))) & 255;
  int b1 = ((int)clamp128(rintf(v[1] / s_x))) & 255;
  int b2 = ((int)clamp128(rintf(v[2] / s_x))) & 255;
  int b3 = ((int)clamp128(rintf(v[3] / s_x))) & 255;
  ((int*)xq8)[i] = b0 | (b1 << 8) | (b2 << 16) | (b3 << 24);
}

// ---------------- Wx GEMM, int8 MFMA (both passes) ----------------
__global__ __launch_bounds__(1024) void k_wx_i8(
    const signed char* __restrict__ xq8, const signed char* __restrict__ wf,
    unsigned* __restrict__ slots, signed char* __restrict__ wxq, int mode) {
  const int t = blockIdx.x;
  const int tid = threadIdx.x, lane = tid & 63, w = tid >> 6;
  const int cl = lane & 15, lh = lane >> 4;

  v4i Bz[4], Br[4], Bn[4];
  #pragma unroll
  for (int kc = 0; kc < 4; ++kc) {
    Bz[kc] = *(const v4i*)(wf + (((w)*4      + kc) * 64 + lane) * 16);
    Br[kc] = *(const v4i*)(wf + (((w + 16)*4 + kc) * 64 + lane) * 16);
    Bn[kc] = *(const v4i*)(wf + (((w + 32)*4 + kc) * 64 + lane) * 16);
  }
  v4i acc[3][4];
  #pragma unroll
  for (int p = 0; p < 3; ++p)
    #pragma unroll
    for (int rt = 0; rt < 4; ++rt) acc[p][rt] = (v4i){0, 0, 0, 0};

  const signed char* xr = xq8 + t * 16384;
  #pragma unroll
  for (int kc = 0; kc < 4; ++kc)
    #pragma unroll
    for (int rt = 0; rt < 4; ++rt) {
      v4i A = *(const v4i*)(xr + (rt * 16 + cl) * 256 + kc * 64 + lh * 16);
      acc[0][rt] = MFMA_I8(A, Bz[kc], acc[0][rt]);
      acc[1][rt] = MFMA_I8(A, Br[kc], acc[1][rt]);
      acc[2][rt] = MFMA_I8(A, Bn[kc], acc[2][rt]);
    }

  if (mode == 0) {
    int mm = 0;
    #pragma unroll
    for (int p = 0; p < 3; ++p)
      #pragma unroll
      for (int rt = 0; rt < 4; ++rt)
        #pragma unroll
        for (int rg = 0; rg < 4; ++rg) mm = max(mm, abs(acc[p][rt][rg]));
    #pragma unroll
    for (int m = 1; m <= 32; m <<= 1) mm = max(mm, __shfl_xor(mm, m, 64));
    if (lane == 0) atomicMax((int*)(slots + 5), mm);
  } else {
    int islot = *(const int*)(slots + 5);
    float maxMf = (float)islot;
    float s_x = fmaxf(__uint_as_float(slots[0]) / 127.0f, 1e-8f);
    float s_W = fmaxf(__uint_as_float(slots[1]) / 127.0f, 1e-8f);
    float s_xW = s_x * s_W;
    float s_wx = fmaxf(s_xW * maxMf / 127.0f, 1e-8f);
    #pragma unroll
    for (int p = 0; p < 3; ++p)
      #pragma unroll
      for (int rt = 0; rt < 4; ++rt) {
        int dw = 0;
        #pragma unroll
        for (int rg = 0; rg < 4; ++rg) {
          float qf = clamp128(rintf((s_xW * (float)acc[p][rt][rg]) / s_wx));
          dw |= (((int)qf) & 255) << (rg * 8);
        }
        ((int*)wxq)[t * 12288 + p * 4096 + rt * 1024 + w * 64 + lh * 16 + cl] = dw;
      }
  }
}

// ---------------- block-local max reduction (single-WG, 3-set ring) --------
// One __syncthreads per round.  Ring distance 3 makes the pre-barrier reset
// of set (r+1)%3 safe: every thread finished reading set r-2 before barrier
// r-1, and tid32 resets only after passing barrier r-1.
template <int NCH>
__device__ __forceinline__ void bred(unsigned* keys, unsigned tag,
                                     unsigned (*lred)[8], int tid, int lane) {
  const int rset = tag % 3;
  #pragma unroll
  for (int c = 0; c < NCH; ++c) {
    unsigned v = keys[c];
    #pragma unroll
    for (int m = 1; m <= 32; m <<= 1)
      v = max(v, (unsigned)__shfl_xor((int)v, m, 64));
    keys[c] = v;
  }
  if (lane == 0) {
    #pragma unroll
    for (int c = 0; c < NCH; ++c) atomicMax(&lred[rset][c], keys[c]);
  } else if (tid == 32) {
    int ns = rset + 1; if (ns == 3) ns = 0;       // pre-zero next ring set
    #pragma unroll
    for (int c = 0; c < 8; ++c) lred[ns][c] = 0u;
  }
  __syncthreads();
  #pragma unroll
  for (int c = 0; c < NCH; ++c) keys[c] = lred[rset][c];
}

// ---------------- the recurrence: ONE workgroup, full 64x256 domain --------
__global__ __launch_bounds__(1024) void k_recur1(
    const signed char* __restrict__ wxq, const signed char* __restrict__ brf,
    const float* __restrict__ bq, const unsigned* __restrict__ slots,
    const float* __restrict__ h0p, float* __restrict__ out) {
  __shared__ signed char ah[64 * 272];     // int8 h rows, pad stride 272
  __shared__ unsigned lred[3][8];          // 3-set ring x 8 channels

  const int tid = threadIdx.x;
  const int lane = tid & 63;
  const int w = tid >> 6;                  // 16 waves: col tiles {w,w+16,w+32}
  const int cl = lane & 15;
  const int lh = lane >> 4;
  const int j = w * 16 + cl;               // h column 0..255
  // site rows: rt*16 + lh*4 + rg,  rt=0..3, rg=0..3  (16 sites/thread)

  if (tid < 24) ((unsigned*)lred)[tid] = 0u;

  float s_x = fmaxf(__uint_as_float(slots[0]) / 127.0f, 1e-8f);
  float s_W = fmaxf(__uint_as_float(slots[1]) / 127.0f, 1e-8f);
  float s_R = fmaxf(__uint_as_float(slots[2]) / 127.0f, 1e-8f);
  float maxM0 = (float)(*(const int*)(slots + 5));
  float s_wx = fmaxf(s_x * s_W * maxM0 / 127.0f, 1e-8f);

  float bxz = bq[j], bxr = bq[j + 256], bxn = bq[j + 512];
  float brz = bq[768 + j], brr = bq[1024 + j], brn = bq[1280 + j];

  // frag base pointers (reloaded per step from L2; not held resident)
  const signed char* pBz = brf + (((w)*4)      * 64 + lane) * 16;
  const signed char* pBr = brf + (((w + 16)*4) * 64 + lane) * 16;
  const signed char* pBn = brf + (((w + 32)*4) * 64 + lane) * 16;
  const int abase = cl * 272 + lh * 16;    // + rt*4352 + kc*64

  float h[4][4];
  #pragma unroll
  for (int rt = 0; rt < 4; ++rt)
    #pragma unroll
    for (int rg = 0; rg < 4; ++rg)
      h[rt][rg] = h0p[(rt * 16 + lh * 4 + rg) * 256 + j];

  __syncthreads();                         // lred zero visible

  unsigned tag = 1;
  float sh;
  {
    float m = 0.0f;
    #pragma unroll
    for (int rt = 0; rt < 4; ++rt)
      #pragma unroll
      for (int rg = 0; rg < 4; ++rg) m = fmaxf(m, fabsf(h[rt][rg]));
    unsigned kk[1] = {__float_as_uint(m)};
    bred<1>(kk, tag++, lred, tid, lane);
    sh = fmaxf(__uint_as_float(kk[0]) / 127.0f, 1e-8f);
    float ish = 1.0f / sh;
    #pragma unroll
    for (int rt = 0; rt < 4; ++rt)
      #pragma unroll
      for (int rg = 0; rg < 4; ++rg)
        ah[(rt * 16 + lh * 4 + rg) * 272 + j] =
            (signed char)(int)rintf(h[rt][rg] * ish);
    __syncthreads();
  }

  for (int t = 0; t < T_STEPS; ++t) {
    // Wx code dwords for all 16 sites x 3 gates (prefetched; used at B/C/D)
    const signed char* wb = wxq + (size_t)t * 49152 + (tid << 2);
    int wv[3][4];
    #pragma unroll
    for (int p = 0; p < 3; ++p)
      #pragma unroll
      for (int rt = 0; rt < 4; ++rt)
        wv[p][rt] = *(const int*)(wb + p * 16384 + rt * 4096);

    // ---- GEMM: 64x768 = ah(64x256,i8) @ R(256x768,i8), exact ----
    v4i accZ[4], accR[4], accN[4];
    #pragma unroll
    for (int rt = 0; rt < 4; ++rt) {
      accZ[rt] = (v4i){0,0,0,0}; accR[rt] = (v4i){0,0,0,0};
      accN[rt] = (v4i){0,0,0,0};
    }
    #pragma unroll
    for (int kc = 0; kc < 4; ++kc) {
      v4i Bz = *(const v4i*)(pBz + kc * 1024);
      v4i Br = *(const v4i*)(pBr + kc * 1024);
      v4i Bn = *(const v4i*)(pBn + kc * 1024);
      #pragma unroll
      for (int rt = 0; rt < 4; ++rt) {
        v4i A = *(const v4i*)(ah + abase + rt * 4352 + kc * 64);
        accZ[rt] = MFMA_I8(A, Bz, accZ[rt]);
        accR[rt] = MFMA_I8(A, Br, accR[rt]);
        accN[rt] = MFMA_I8(A, Bn, accN[rt]);
      }
    }

    // ---- R1: global max|acc| ----
    int mm = 0;
    #pragma unroll
    for (int rt = 0; rt < 4; ++rt)
      #pragma unroll
      for (int rg = 0; rg < 4; ++rg)
        mm = max(mm, max(abs(accZ[rt][rg]),
                         max(abs(accR[rt][rg]), abs(accN[rt][rg]))));
    unsigned kk[5];
    kk[0] = (unsigned)mm;
    bred<1>(kk, tag++, lred, tid, lane);
    float maxMf = (float)(int)kk[0];
    float s_Rh = fmaxf(sh * s_R * maxMf / 127.0f, 1e-8f);
    float fRh = (sh * s_R) / s_Rh;

    // ---- stage B: maxes of z_pre, r_pre, Rh_n+br_n; pack acc codes ----
    int kzp[4], krp[4], knp[4];            // packed 8-bit acc codes per rt
    float az = 0.0f, ar = 0.0f, an = 0.0f;
    float mzs = -3.402823466e38f, mrs = -3.402823466e38f;
    #pragma unroll
    for (int rt = 0; rt < 4; ++rt) {
      int pz = 0, pr = 0, pn = 0;
      #pragma unroll
      for (int rg = 0; rg < 4; ++rg) {
        float fz = rintf((float)accZ[rt][rg] * fRh);
        float fr = rintf((float)accR[rt][rg] * fRh);
        float fn = rintf((float)accN[rt][rg] * fRh);
        pz |= (((int)fz) & 255) << (rg * 8);
        pr |= (((int)fr) & 255) << (rg * 8);
        pn |= (((int)fn) & 255) << (rg * 8);
        float wz = s_wx * sgnb(wv[0][rt], rg);
        float wr = s_wx * sgnb(wv[1][rt], rg);
        float a1 = ((wz + bxz) + (s_Rh * fz)) + brz;
        float a2 = ((wr + bxr) + (s_Rh * fr)) + brr;
        float a3 = (s_Rh * fn) + brn;
        az = fmaxf(az, fabsf(a1)); ar = fmaxf(ar, fabsf(a2));
        an = fmaxf(an, fabsf(a3));
        mzs = fmaxf(mzs, a1); mrs = fmaxf(mrs, a2);
      }
      kzp[rt] = pz; krp[rt] = pr; knp[rt] = pn;
    }
    kk[0] = __float_as_uint(az); kk[1] = __float_as_uint(ar);
    kk[2] = __float_as_uint(an); kk[3] = skey(mzs); kk[4] = skey(mrs);
    bred<5>(kk, tag++, lred, tid, lane);
    float s1 = fmaxf(__uint_as_float(kk[0]) / 127.0f, 1e-8f), i1 = 1.0f / s1;
    float s2 = fmaxf(__uint_as_float(kk[1]) / 127.0f, 1e-8f), i2 = 1.0f / s2;
    float s3 = fmaxf(__uint_as_float(kk[2]) / 127.0f, 1e-8f), i3 = 1.0f / s3;
    float zq_max = s1 * rintf(sdec(kk[3]) * i1);
    float rq_max = s2 * rintf(sdec(kk[4]) * i2);
    float s4 = fmaxf(sigmoidf_(zq_max) / 127.0f, 1e-8f), i4 = 1.0f / s4;
    float s5 = fmaxf(sigmoidf_(rq_max) / 127.0f, 1e-8f), i5 = 1.0f / s5;

    // ---- stage C: reconstruct pre-acts; pack zf/rv/nb codes; m6 ----
    int kz2p[4], k2p[4], k3p[4];
    float m6 = 0.0f;
    #pragma unroll
    for (int rt = 0; rt < 4; ++rt) {
      int pz2 = 0, p2 = 0, p3 = 0;
      #pragma unroll
      for (int rg = 0; rg < 4; ++rg) {
        float wz = s_wx * sgnb(wv[0][rt], rg);
        float zp = ((wz + bxz) + (s_Rh * sgnb(kzp[rt], rg))) + brz;
        float wr = s_wx * sgnb(wv[1][rt], rg);
        float rp = ((wr + bxr) + (s_Rh * sgnb(krp[rt], rg))) + brr;
        float nb = (s_Rh * sgnb(knp[rt], rg)) + brn;
        float zq = s1 * rintf(zp * i1);
        float rq = s2 * rintf(rp * i2);
        float zv = sigmoidf_(zq);
        float rv = sigmoidf_(rq);
        float fz2 = rintf(zv * i4);
        float f2  = rintf(rv * i5);
        float f3  = rintf(nb * i3);
        pz2 |= (((int)fz2) & 255) << (rg * 8);
        p2  |= (((int)f2)  & 255) << (rg * 8);
        p3  |= (((int)f3)  & 255) << (rg * 8);
        float rr = (s5 * f2) * (s3 * f3);
        m6 = fmaxf(m6, fabsf(rr));
      }
      kz2p[rt] = pz2; k2p[rt] = p2; k3p[rt] = p3;
    }
    kk[0] = __float_as_uint(m6);
    bred<1>(kk, tag++, lred, tid, lane);
    float s6 = fmaxf(__uint_as_float(kk[0]) / 127.0f, 1e-8f), i6 = 1.0f / s6;

    // ---- stage D: g_pre (kept raw f32 across the m7 round) ----
    float gp[4][4];
    float m7 = 0.0f;
    #pragma unroll
    for (int rt = 0; rt < 4; ++rt)
      #pragma unroll
      for (int rg = 0; rg < 4; ++rg) {
        float rr = (s5 * sgnb(k2p[rt], rg)) * (s3 * sgnb(k3p[rt], rg));
        float rrq = s6 * rintf(rr * i6);
        float wn = s_wx * sgnb(wv[2][rt], rg);
        float g = (wn + bxn) + rrq;
        gp[rt][rg] = g;
        m7 = fmaxf(m7, fabsf(g));
      }
    kk[0] = __float_as_uint(m7);
    bred<1>(kk, tag++, lred, tid, lane);
    float m7g = __uint_as_float(kk[0]);
    float s7 = fmaxf(m7g / 127.0f, 1e-8f), i7 = 1.0f / s7;
    float gq_max = s7 * rintf(m7g * i7);
    float s8 = fmaxf(tanhf_(gq_max) / 127.0f, 1e-8f), i8v = 1.0f / s8;

    // ---- stage E: g codes; mo, mn ----
    int kgp_[4];
    float mo = 0.0f, mn = 0.0f;
    #pragma unroll
    for (int rt = 0; rt < 4; ++rt) {
      int pg = 0;
      #pragma unroll
      for (int rg = 0; rg < 4; ++rg) {
        float gpq = s7 * rintf(gp[rt][rg] * i7);
        float gv = tanhf_(gpq);
        float fg = rintf(gv * i8v);
        pg |= (((int)fg) & 255) << (rg * 8);
        float zf = s4 * sgnb(kz2p[rt], rg);
        float o = zf * h[rt][rg];
        float n = (1.0f - zf) * (s8 * fg);
        mo = fmaxf(mo, fabsf(o)); mn = fmaxf(mn, fabsf(n));
      }
      kgp_[rt] = pg;
    }
    kk[0] = __float_as_uint(mo); kk[1] = __float_as_uint(mn);
    bred<2>(kk, tag++, lred, tid, lane);
    float s9  = fmaxf(__uint_as_float(kk[0]) / 127.0f, 1e-8f), i9  = 1.0f / s9;
    float s10 = fmaxf(__uint_as_float(kk[1]) / 127.0f, 1e-8f), i10 = 1.0f / s10;

    // ---- stage F: h_new, write output; mh ----
    float mh = 0.0f;
    #pragma unroll
    for (int rt = 0; rt < 4; ++rt)
      #pragma unroll
      for (int rg = 0; rg < 4; ++rg) {
        float zf = s4 * sgnb(kz2p[rt], rg);
        float o = zf * h[rt][rg];
        float n = (1.0f - zf) * (s8 * sgnb(kgp_[rt], rg));
        float oq = s9  * rintf(o * i9);
        float nq = s10 * rintf(n * i10);
        float hn = oq + nq;
        h[rt][rg] = hn;
        mh = fmaxf(mh, fabsf(hn));
        out[t * 16384 + (rt * 16 + lh * 4 + rg) * 256 + j] = hn;
      }
    kk[0] = __float_as_uint(mh);
    bred<1>(kk, tag++, lred, tid, lane);
    sh = fmaxf(__uint_as_float(kk[0]) / 127.0f, 1e-8f);
    float ish = 1.0f / sh;
    #pragma unroll
    for (int rt = 0; rt < 4; ++rt)
      #pragma unroll
      for (int rg = 0; rg < 4; ++rg)
        ah[(rt * 16 + lh * 4 + rg) * 272 + j] =
            (signed char)(int)rintf(h[rt][rg] * ish);
    __syncthreads();                       // ah ready for next step
  }

  // h_last
  #pragma unroll
  for (int rt = 0; rt < 4; ++rt)
    #pragma unroll
    for (int rg = 0; rg < 4; ++rg)
      out[OUT_MAIN_FLOATS + (rt * 16 + lh * 4 + rg) * 256 + j] = h[rt][rg];
}

// ============================================================================
extern "C" void kernel_launch(void* const* d_in, const int* in_sizes, int n_in,
                              void* d_out, int out_size, void* d_ws, size_t ws_size,
                              hipStream_t stream) {
  const float* x   = (const float*)d_in[0];   // (1024,64,256)
  const float* wih = (const float*)d_in[1];   // (768,256)
  const float* whh = (const float*)d_in[2];   // (768,256)
  const float* bih = (const float*)d_in[3];   // (768,)
  const float* bhh = (const float*)d_in[4];   // (768,)
  const float* h0  = (const float*)d_in[5];   // (64,256)
  float* out = (float*)d_out;

  // d_ws layout: [0..255] absmax slots, [4096..] bq, [10240..] fragment F.
  unsigned* slots = (unsigned*)d_ws;
  float* bq       = (float*)((char*)d_ws + 4096);
  signed char* F  = (signed char*)d_ws + 10240;          // 196,608 B

  signed char* wxq = (signed char*)d_out + WXQ_DOUT_OFF; // tail of d_out
  signed char* xq8 = (signed char*)d_out;                // head (dead later)

  hipMemsetAsync(d_ws, 0, 4096, stream);

  k_absmax<<<dim3(1024), dim3(256), 0, stream>>>(x,   16777216 / 4, slots + 0);
  k_absmax<<<dim3(96),   dim3(256), 0, stream>>>(wih, 196608 / 4,   slots + 1);
  k_absmax<<<dim3(96),   dim3(256), 0, stream>>>(whh, 196608 / 4,   slots + 2);
  k_absmax<<<dim3(1),    dim3(256), 0, stream>>>(bih, 768 / 4,      slots + 3);
  k_absmax<<<dim3(1),    dim3(256), 0, stream>>>(bhh, 768 / 4,      slots + 4);

  k_frag<<<dim3(192), dim3(256), 0, stream>>>(wih, slots, 1, F);   // W frags
  k_bias<<<dim3(1), dim3(768), 0, stream>>>(bih, bhh, slots, bq);
  k_xq<<<dim3(16384), dim3(256), 0, stream>>>(x, slots, xq8, 4194304);

  k_wx_i8<<<dim3(1024), dim3(1024), 0, stream>>>(xq8, F, slots, wxq, 0);
  k_wx_i8<<<dim3(1024), dim3(1024), 0, stream>>>(xq8, F, slots, wxq, 1);

  k_frag<<<dim3(192), dim3(256), 0, stream>>>(whh, slots, 2, F);   // R frags

  k_recur1<<<dim3(1), dim3(1024), 0, stream>>>(wxq, F, bq, slots, h0, out);
}

// Round 4
// 18245.474 us; speedup vs baseline: 1.7274x; 1.7274x over previous
//
#include <hip/hip_runtime.h>
#include <cstdint>
#include <cstddef>

// ============================================================================
// QuantGRU on MI355X — round 6
//
// Post-mortems: r4 (same-XCD sc0 exchange) = null => fabric latency is NOT the
// round bottleneck.  r5 (single-WG) = 31.5ms => full-domain VALU is ~19us/step
// on one CU, and a reduction round costs ~1.5-1.9us even block-local => the
// round cost is the reduce+barrier STRUCTURE, not the fabric.
//
// This round: 4 WGs (r2's proven compute body, byte-identical numerics) with a
// PER-WAVE-PUBLISH exchange:
//  * After the 64-lane shuffle butterfly every lane holds the wave max, so
//    each wave immediately publishes {tag, wavemax} to its own slot (16
//    slots/WG/round) via the r2-PROVEN relaxed AGENT 8B atomic store.
//  * Dedicated poller lanes (3 remote WGs x 16 waves x NCH <= 240 of the 960
//    non-wave0 lanes) spin on the slots and ds_atomicMax partials into LDS.
//  * Own-WG partials go straight to LDS atomicMax from each wave.
//  * ONE barrier per round (was 2): no pre-publish internal reduce, wave skew
//    overlaps remote visibility.  Ring-of-3 LDS sets + parity-2 slots +
//    monotone tags keep the no-ABA argument (reads of set r precede bar(r) <=
//    bar(r+1) <= any round r+2 write).
//  * No election, no sc0/sc1 asm — only proven primitives.
// ============================================================================

typedef int   v4i __attribute__((ext_vector_type(4)));
typedef float v4f __attribute__((ext_vector_type(4)));

#define T_STEPS 1024
#define OUT_MAIN_FLOATS (1024*64*256)          // 16,777,216
#define WXQ_DOUT_OFF 16842752                  // out_bytes(67,174,400) - 50,331,648

__device__ __forceinline__ float clamp128(float x) {
  return fminf(fmaxf(x, -128.0f), 127.0f);
}
__device__ __forceinline__ int permj(int j) {           // haste row -> pt row
  return j < 256 ? j + 256 : (j < 512 ? j - 256 : j);
}
__device__ __forceinline__ float sigmoidf_(float x) {
  return __fdividef(1.0f, 1.0f + __expf(-x));
}
__device__ __forceinline__ float tanhf_(float x) {
  float e = __expf(-2.0f * fabsf(x));
  float t = __fdividef(1.0f - e, 1.0f + e);
  return copysignf(t, x);
}
// monotone uint key for signed float max
__device__ __forceinline__ unsigned skey(float x) {
  unsigned u = __float_as_uint(x);
  return (u & 0x80000000u) ? ~u : (u | 0x80000000u);
}
__device__ __forceinline__ float sdec(unsigned k) {
  unsigned u = (k & 0x80000000u) ? (k ^ 0x80000000u) : ~k;
  return __uint_as_float(u);
}
__device__ __forceinline__ float wave_amax(float v) {
  #pragma unroll
  for (int m = 1; m <= 32; m <<= 1) v = fmaxf(v, __shfl_xor(v, m, 64));
  return v;
}

#define MFMA_I8(a, b, c) __builtin_amdgcn_mfma_i32_16x16x64_i8(a, b, c, 0, 0, 0)

// ---------------- absmax over a float tensor (n4 = n/4) ----------------
__global__ void k_absmax(const float* __restrict__ p, int n4, unsigned* slot) {
  int i = blockIdx.x * blockDim.x + threadIdx.x;
  int stride = gridDim.x * blockDim.x;
  const v4f* p4 = (const v4f*)p;
  float m = 0.0f;
  for (; i < n4; i += stride) {
    v4f v = p4[i];
    m = fmaxf(m, fmaxf(fmaxf(fabsf(v[0]), fabsf(v[1])),
                       fmaxf(fabsf(v[2]), fabsf(v[3]))));
  }
  m = wave_amax(m);
  if ((threadIdx.x & 63) == 0) atomicMax(slot, __float_as_uint(m));
}

// ---------------- 768x256 weight -> int8 MFMA B-fragments ----------------
__global__ void k_frag(const float* __restrict__ src,
                       const unsigned* __restrict__ slots, int slot_idx,
                       signed char* __restrict__ dst) {
  int id = blockIdx.x * 256 + threadIdx.x;   // 0..49151
  float s = fmaxf(__uint_as_float(slots[slot_idx]) / 127.0f, 1e-8f);
  int bq   = id & 3;
  int lane = (id >> 2) & 63;
  int kc   = (id >> 8) & 3;
  int ct   = id >> 10;
  int n = ct * 16 + (lane & 15);
  int k = kc * 64 + (lane >> 4) * 16 + bq * 4;
  const float* p = src + permj(n) * 256 + k;
  int b0 = ((int)clamp128(rintf(p[0] / s))) & 255;
  int b1 = ((int)clamp128(rintf(p[1] / s))) & 255;
  int b2 = ((int)clamp128(rintf(p[2] / s))) & 255;
  int b3 = ((int)clamp128(rintf(p[3] / s))) & 255;
  ((int*)dst)[id] = b0 | (b1 << 8) | (b2 << 16) | (b3 << 24);
}

// ---------------- biases: reorder + fake-quant (dequantized fp32) ----------
__global__ void k_bias(const float* __restrict__ bih, const float* __restrict__ bhh,
                       const unsigned* __restrict__ slots, float* __restrict__ bqo) {
  int j = threadIdx.x;               // 0..767
  float s_bx = fmaxf(__uint_as_float(slots[3]) / 127.0f, 1e-8f);
  float s_br = fmaxf(__uint_as_float(slots[4]) / 127.0f, 1e-8f);
  int pr = permj(j);
  bqo[j]       = s_bx * clamp128(rintf(bih[pr] / s_bx));
  bqo[768 + j] = s_br * clamp128(rintf(bhh[pr] / s_br));
}

// ---------------- quantize x -> int8 ----------------
__global__ void k_xq(const float* __restrict__ x, const unsigned* __restrict__ slots,
                     signed char* __restrict__ xq8, int n4) {
  int i = blockIdx.x * blockDim.x + threadIdx.x;
  if (i >= n4) return;
  float s_x = fmaxf(__uint_as_float(slots[0]) / 127.0f, 1e-8f);
  v4f v = ((const v4f*)x)[i];
  int b0 = ((int)clamp128(rintf(v[0] / s_x))) & 255;
  int b1 = ((int)clamp128(rintf(v[1] / s_x))) & 255;
  int b2 = ((int)clamp128(rintf(v[2] / s_x))) & 255;
  int b3 = ((int)clamp128(rintf(v[3] / s_x))) & 255;
  ((int*)xq8)[i] = b0 | (b1 << 8) | (b2 << 16) | (b3 << 24);
}

// ---------------- Wx GEMM, int8 MFMA (both passes) ----------------
__global__ __launch_bounds__(1024) void k_wx_i8(
    const signed char* __restrict__ xq8, const signed char* __restrict__ wf,
    unsigned* __restrict__ slots, signed char* __restrict__ wxq, int mode) {
  const int t = blockIdx.x;
  const int tid = threadIdx.x, lane = tid & 63, w = tid >> 6;
  const int cl = lane & 15, lh = lane >> 4;

  v4i Bz[4], Br[4], Bn[4];
  #pragma unroll
  for (int kc = 0; kc < 4; ++kc) {
    Bz[kc] = *(const v4i*)(wf + (((w)*4      + kc) * 64 + lane) * 16);
    Br[kc] = *(const v4i*)(wf + (((w + 16)*4 + kc) * 64 + lane) * 16);
    Bn[kc] = *(const v4i*)(wf + (((w + 32)*4 + kc) * 64 + lane) * 16);
  }
  v4i acc[3][4];
  #pragma unroll
  for (int p = 0; p < 3; ++p)
    #pragma unroll
    for (int rt = 0; rt < 4; ++rt) acc[p][rt] = (v4i){0, 0, 0, 0};

  const signed char* xr = xq8 + t * 16384;
  #pragma unroll
  for (int kc = 0; kc < 4; ++kc)
    #pragma unroll
    for (int rt = 0; rt < 4; ++rt) {
      v4i A = *(const v4i*)(xr + (rt * 16 + cl) * 256 + kc * 64 + lh * 16);
      acc[0][rt] = MFMA_I8(A, Bz[kc], acc[0][rt]);
      acc[1][rt] = MFMA_I8(A, Br[kc], acc[1][rt]);
      acc[2][rt] = MFMA_I8(A, Bn[kc], acc[2][rt]);
    }

  if (mode == 0) {
    int mm = 0;
    #pragma unroll
    for (int p = 0; p < 3; ++p)
      #pragma unroll
      for (int rt = 0; rt < 4; ++rt)
        #pragma unroll
        for (int rg = 0; rg < 4; ++rg) mm = max(mm, abs(acc[p][rt][rg]));
    #pragma unroll
    for (int m = 1; m <= 32; m <<= 1) mm = max(mm, __shfl_xor(mm, m, 64));
    if (lane == 0) atomicMax((int*)(slots + 5), mm);
  } else {
    int islot = *(const int*)(slots + 5);
    float maxMf = (float)islot;
    float s_x = fmaxf(__uint_as_float(slots[0]) / 127.0f, 1e-8f);
    float s_W = fmaxf(__uint_as_float(slots[1]) / 127.0f, 1e-8f);
    float s_xW = s_x * s_W;
    float s_wx = fmaxf(s_xW * maxMf / 127.0f, 1e-8f);
    #pragma unroll
    for (int p = 0; p < 3; ++p)
      #pragma unroll
      for (int rt = 0; rt < 4; ++rt) {
        int dw = 0;
        #pragma unroll
        for (int rg = 0; rg < 4; ++rg) {
          float qf = clamp128(rintf((s_xW * (float)acc[p][rt][rg]) / s_wx));
          dw |= (((int)qf) & 255) << (rg * 8);
        }
        ((int*)wxq)[t * 12288 + p * 4096 + rt * 1024 + w * 64 + lh * 16 + cl] = dw;
      }
  }
}

// ---------------- cross-WG max exchange, PER-WAVE publish ------------------
// Slot = aligned 8B {tag:hi32, value:lo32}; one per (parity, wg, wave, ch),
// ch stride 5 (NCH <= 5).  After the xor-butterfly every lane holds the wave
// max, so lanes 0..NCH-1 of EVERY wave publish their channel's partial with a
// relaxed AGENT store (r2-proven primitive) AND ds_atomicMax it into the LDS
// result set.  Poller lanes (tid 64..64+3*16*NCH) spin on one remote
// (wg,wave,ch) slot each until hi32==tag, then ds_atomicMax the value.
// ONE barrier per round.  Ring-of-3 LDS sets: the reset of set (r+1)%3 in
// round r is ordered after bar(r-1), which follows all reads of set (r-2)%3
// (same set).  Slot overwrite (round r -> r+2, same parity) is ordered after
// bar(r+1), which follows every poller's round-r consumption.  No ABA;
// monotone tags make stale reads unconsumable.
template <int NCH>
__device__ __forceinline__ void xchg(unsigned* keys, unsigned tag,
    unsigned (*lred)[8], unsigned long long* gslot, int wg, int tid, int lane,
    int w) {
  const int rset = tag % 3;
  #pragma unroll
  for (int c = 0; c < NCH; ++c) {
    unsigned v = keys[c];
    #pragma unroll
    for (int m = 1; m <= 32; m <<= 1)
      v = max(v, (unsigned)__shfl_xor((int)v, m, 64));
    keys[c] = v;
  }
  const int par = tag & 1;
  if (lane < NCH) {
    // select this lane's channel with static indexing (no scratch)
    unsigned kv = keys[0];
    #pragma unroll
    for (int c = 1; c < NCH; ++c) if (lane == c) kv = keys[c];
    unsigned long long v =
        ((unsigned long long)tag << 32) | (unsigned long long)kv;
    __hip_atomic_store(&gslot[((par * 4 + wg) * 16 + w) * 5 + lane], v,
                       __ATOMIC_RELAXED, __HIP_MEMORY_SCOPE_AGENT);
    atomicMax(&lred[rset][lane], kv);
  } else if (tid == 32) {
    int ns = rset + 1; if (ns == 3) ns = 0;       // pre-zero next ring set
    #pragma unroll
    for (int c = 0; c < 8; ++c) lred[ns][c] = 0u;
  }
  if (tid >= 64 && tid < 64 + 3 * 16 * NCH) {
    int idx = tid - 64;
    int owi = idx / (16 * NCH);
    int rem = idx - owi * (16 * NCH);
    int wv = rem / NCH;
    int ch = rem - wv * NCH;
    int ow = owi + (owi >= wg ? 1 : 0);
    unsigned long long* p = &gslot[((par * 4 + ow) * 16 + wv) * 5 + ch];
    unsigned long long v;
    do {
      v = __hip_atomic_load(p, __ATOMIC_RELAXED, __HIP_MEMORY_SCOPE_AGENT);
    } while ((unsigned)(v >> 32) != tag);
    atomicMax(&lred[rset][ch], (unsigned)v);
  }
  __syncthreads();
  #pragma unroll
  for (int c = 0; c < NCH; ++c) keys[c] = lred[rset][c];
}

// ---------------- the recurrence: 4 workgroups, 16 batch rows each ---------
__global__ __launch_bounds__(1024) void k_recur4b(
    const signed char* __restrict__ wxq, const signed char* __restrict__ brf,
    const float* __restrict__ bq, const unsigned* __restrict__ slots,
    const float* __restrict__ h0p, float* __restrict__ out,
    unsigned long long* __restrict__ gslot) {
  __shared__ signed char ah[16 * 272];     // int8 h rows (WG-local), pad stride
  __shared__ unsigned lred[3][8];          // 3-set ring x 8 channels

  const int tid = threadIdx.x;
  const int lane = tid & 63;
  const int w = tid >> 6;                  // 16 waves: col tiles {w, w+16, w+32}
  const int cl = lane & 15;
  const int lh = lane >> 4;
  const int wg = blockIdx.x;               // 0..3 -> batch rows 16*wg..+15
  const int j = w * 16 + cl;               // h column 0..255
  const int brow = wg * 16 + lh * 4;       // +rg = global batch row

  if (tid < 24) ((unsigned*)lred)[tid] = 0u;

  float s_x = fmaxf(__uint_as_float(slots[0]) / 127.0f, 1e-8f);
  float s_W = fmaxf(__uint_as_float(slots[1]) / 127.0f, 1e-8f);
  float s_R = fmaxf(__uint_as_float(slots[2]) / 127.0f, 1e-8f);
  float maxM0 = (float)(*(const int*)(slots + 5));
  float s_wx = fmaxf(s_x * s_W * maxM0 / 127.0f, 1e-8f);

  float bxz = bq[j], bxr = bq[j + 256], bxn = bq[j + 512];
  float brz = bq[768 + j], brr = bq[1024 + j], brn = bq[1280 + j];

  v4i Bz[4], Br[4], Bn[4];                 // R fragments, resident
  #pragma unroll
  for (int kc = 0; kc < 4; ++kc) {
    Bz[kc] = *(const v4i*)(brf + (((w)*4      + kc) * 64 + lane) * 16);
    Br[kc] = *(const v4i*)(brf + (((w + 16)*4 + kc) * 64 + lane) * 16);
    Bn[kc] = *(const v4i*)(brf + (((w + 32)*4 + kc) * 64 + lane) * 16);
  }

  float h[4];
  #pragma unroll
  for (int rg = 0; rg < 4; ++rg) h[rg] = h0p[(brow + rg) * 256 + j];

  __syncthreads();                         // lred zero visible

  unsigned tag = 1;
  float sh;
  {
    float m = fmaxf(fmaxf(fabsf(h[0]), fabsf(h[1])),
                    fmaxf(fabsf(h[2]), fabsf(h[3])));
    unsigned kk[1] = {__float_as_uint(m)};
    xchg<1>(kk, tag++, lred, gslot, wg, tid, lane, w);
    sh = fmaxf(__uint_as_float(kk[0]) / 127.0f, 1e-8f);
    float ish = 1.0f / sh;
    #pragma unroll
    for (int rg = 0; rg < 4; ++rg)
      ah[(lh * 4 + rg) * 272 + j] = (signed char)(int)rintf(h[rg] * ish);
    __syncthreads();
  }

  for (int t = 0; t < T_STEPS; ++t) {
    // Wx bytes for this step (coalesced dwords)
    const signed char* wb = wxq + (size_t)t * 49152 + (wg << 12) + (tid << 2);
    int wvz = *(const int*)(wb);
    int wvr = *(const int*)(wb + 16384);
    int wvn = *(const int*)(wb + 32768);

    // ---- GEMM: 16x768 = ah(16x256,i8) @ R(256x768,i8), exact ----
    v4i az4 = {0,0,0,0}, ar4 = {0,0,0,0}, an4 = {0,0,0,0};
    #pragma unroll
    for (int kc = 0; kc < 4; ++kc) {
      v4i A = *(const v4i*)(ah + cl * 272 + kc * 64 + lh * 16);
      az4 = MFMA_I8(A, Bz[kc], az4);
      ar4 = MFMA_I8(A, Br[kc], ar4);
      an4 = MFMA_I8(A, Bn[kc], an4);
    }

    // ---- R1: global max|acc| ----
    int mm = 0;
    #pragma unroll
    for (int rg = 0; rg < 4; ++rg)
      mm = max(mm, max(abs(az4[rg]), max(abs(ar4[rg]), abs(an4[rg]))));
    unsigned kk[5];
    kk[0] = (unsigned)mm;
    xchg<1>(kk, tag++, lred, gslot, wg, tid, lane, w);
    float maxMf = (float)(int)kk[0];
    float s_Rh = fmaxf(sh * s_R * maxMf / 127.0f, 1e-8f);
    float fRh = (sh * s_R) / s_Rh;

    // ---- stage B: z_pre, r_pre, Rh_n+br_n + abs/signed maxes ----
    float zp[4], rp[4], nb[4];
    float az = 0.0f, ar = 0.0f, an = 0.0f;
    float mzs = -3.402823466e38f, mrs = -3.402823466e38f;
    #pragma unroll
    for (int rg = 0; rg < 4; ++rg) {
      float Rz = s_Rh * rintf((float)az4[rg] * fRh);
      float Rr = s_Rh * rintf((float)ar4[rg] * fRh);
      float Rn = s_Rh * rintf((float)an4[rg] * fRh);
      float wz = s_wx * (float)((signed char)(wvz >> (rg * 8)));
      float wr = s_wx * (float)((signed char)(wvr >> (rg * 8)));
      float a1 = ((wz + bxz) + Rz) + brz;
      float a2 = ((wr + bxr) + Rr) + brr;
      float a3 = Rn + brn;
      zp[rg] = a1; rp[rg] = a2; nb[rg] = a3;
      az = fmaxf(az, fabsf(a1)); ar = fmaxf(ar, fabsf(a2));
      an = fmaxf(an, fabsf(a3));
      mzs = fmaxf(mzs, a1); mrs = fmaxf(mrs, a2);
    }
    kk[0] = __float_as_uint(az); kk[1] = __float_as_uint(ar);
    kk[2] = __float_as_uint(an); kk[3] = skey(mzs); kk[4] = skey(mrs);
    xchg<5>(kk, tag++, lred, gslot, wg, tid, lane, w);
    float s1 = fmaxf(__uint_as_float(kk[0]) / 127.0f, 1e-8f), i1 = 1.0f / s1;
    float s2 = fmaxf(__uint_as_float(kk[1]) / 127.0f, 1e-8f), i2 = 1.0f / s2;
    float s3 = fmaxf(__uint_as_float(kk[2]) / 127.0f, 1e-8f), i3 = 1.0f / s3;
    float zq_max = s1 * rintf(sdec(kk[3]) * i1);
    float rq_max = s2 * rintf(sdec(kk[4]) * i2);
    float s4 = fmaxf(sigmoidf_(zq_max) / 127.0f, 1e-8f), i4 = 1.0f / s4;
    float s5 = fmaxf(sigmoidf_(rq_max) / 127.0f, 1e-8f), i5 = 1.0f / s5;

    // ---- stage C: z final, rRh ----
    float zf[4], rr_[4];
    float m6 = 0.0f;
    #pragma unroll
    for (int rg = 0; rg < 4; ++rg) {
      float zq = s1 * rintf(zp[rg] * i1);
      float rq = s2 * rintf(rp[rg] * i2);
      float zv = sigmoidf_(zq);
      float rv = sigmoidf_(rq);
      zf[rg] = s4 * rintf(zv * i4);
      float rq2 = s5 * rintf(rv * i5);
      float nbq = s3 * rintf(nb[rg] * i3);
      float rr = rq2 * nbq;
      rr_[rg] = rr;
      m6 = fmaxf(m6, fabsf(rr));
    }
    kk[0] = __float_as_uint(m6);
    xchg<1>(kk, tag++, lred, gslot, wg, tid, lane, w);
    float s6 = fmaxf(__uint_as_float(kk[0]) / 127.0f, 1e-8f), i6 = 1.0f / s6;

    // ---- stage D: g_pre ----
    float gp[4];
    float m7 = 0.0f;
    #pragma unroll
    for (int rg = 0; rg < 4; ++rg) {
      float rrq = s6 * rintf(rr_[rg] * i6);
      float wn = s_wx * (float)((signed char)(wvn >> (rg * 8)));
      float g = (wn + bxn) + rrq;
      gp[rg] = g;
      m7 = fmaxf(m7, fabsf(g));
    }
    kk[0] = __float_as_uint(m7);
    xchg<1>(kk, tag++, lred, gslot, wg, tid, lane, w);
    float m7g = __uint_as_float(kk[0]);
    float s7 = fmaxf(m7g / 127.0f, 1e-8f), i7 = 1.0f / s7;
    float gq_max = s7 * rintf(m7g * i7);
    float s8 = fmaxf(tanhf_(gq_max) / 127.0f, 1e-8f), i8v = 1.0f / s8;

    // ---- stage E: g, old/new contribs ----
    float ov[4], nv[4];
    float mo = 0.0f, mn = 0.0f;
    #pragma unroll
    for (int rg = 0; rg < 4; ++rg) {
      float gpq = s7 * rintf(gp[rg] * i7);
      float gv = tanhf_(gpq);
      float gq = s8 * rintf(gv * i8v);
      float o = zf[rg] * h[rg];
      float n = (1.0f - zf[rg]) * gq;
      ov[rg] = o; nv[rg] = n;
      mo = fmaxf(mo, fabsf(o)); mn = fmaxf(mn, fabsf(n));
    }
    kk[0] = __float_as_uint(mo); kk[1] = __float_as_uint(mn);
    xchg<2>(kk, tag++, lred, gslot, wg, tid, lane, w);
    float s9  = fmaxf(__uint_as_float(kk[0]) / 127.0f, 1e-8f), i9  = 1.0f / s9;
    float s10 = fmaxf(__uint_as_float(kk[1]) / 127.0f, 1e-8f), i10 = 1.0f / s10;

    // ---- stage F: h_new, write output ----
    float mh = 0.0f;
    #pragma unroll
    for (int rg = 0; rg < 4; ++rg) {
      float oq = s9  * rintf(ov[rg] * i9);
      float nq = s10 * rintf(nv[rg] * i10);
      float hn = oq + nq;
      h[rg] = hn;
      mh = fmaxf(mh, fabsf(hn));
      out[t * 16384 + (brow + rg) * 256 + j] = hn;
    }
    kk[0] = __float_as_uint(mh);
    xchg<1>(kk, tag++, lred, gslot, wg, tid, lane, w);
    sh = fmaxf(__uint_as_float(kk[0]) / 127.0f, 1e-8f);
    float ish = 1.0f / sh;
    #pragma unroll
    for (int rg = 0; rg < 4; ++rg)
      ah[(lh * 4 + rg) * 272 + j] = (signed char)(int)rintf(h[rg] * ish);
    __syncthreads();                       // ah ready for next step (block-local)
  }

  // h_last
  #pragma unroll
  for (int rg = 0; rg < 4; ++rg)
    out[OUT_MAIN_FLOATS + (brow + rg) * 256 + j] = h[rg];
}

// ============================================================================
extern "C" void kernel_launch(void* const* d_in, const int* in_sizes, int n_in,
                              void* d_out, int out_size, void* d_ws, size_t ws_size,
                              hipStream_t stream) {
  const float* x   = (const float*)d_in[0];   // (1024,64,256)
  const float* wih = (const float*)d_in[1];   // (768,256)
  const float* whh = (const float*)d_in[2];   // (768,256)
  const float* bih = (const float*)d_in[3];   // (768,)
  const float* bhh = (const float*)d_in[4];   // (768,)
  const float* h0  = (const float*)d_in[5];   // (64,256)
  float* out = (float*)d_out;

  // d_ws layout: [0..255] absmax slots; [512..5631] tagged exchange slots
  // (2 parity x 4 wg x 16 wave x 5 ch x 8B = 5120B); [6144..12287] bq;
  // [12288..208895] fragment buffer F (196,608B).
  unsigned* slots = (unsigned*)d_ws;
  unsigned long long* gslot = (unsigned long long*)((char*)d_ws + 512);
  float* bq       = (float*)((char*)d_ws + 6144);
  signed char* F  = (signed char*)d_ws + 12288;

  signed char* wxq = (signed char*)d_out + WXQ_DOUT_OFF; // tail of d_out
  signed char* xq8 = (signed char*)d_out;                // head (dead later)

  hipMemsetAsync(d_ws, 0, 6144, stream);   // zero slots + exchange slots

  k_absmax<<<dim3(1024), dim3(256), 0, stream>>>(x,   16777216 / 4, slots + 0);
  k_absmax<<<dim3(96),   dim3(256), 0, stream>>>(wih, 196608 / 4,   slots + 1);
  k_absmax<<<dim3(96),   dim3(256), 0, stream>>>(whh, 196608 / 4,   slots + 2);
  k_absmax<<<dim3(1),    dim3(256), 0, stream>>>(bih, 768 / 4,      slots + 3);
  k_absmax<<<dim3(1),    dim3(256), 0, stream>>>(bhh, 768 / 4,      slots + 4);

  k_frag<<<dim3(192), dim3(256), 0, stream>>>(wih, slots, 1, F);   // W frags
  k_bias<<<dim3(1), dim3(768), 0, stream>>>(bih, bhh, slots, bq);
  k_xq<<<dim3(16384), dim3(256), 0, stream>>>(x, slots, xq8, 4194304);

  k_wx_i8<<<dim3(1024), dim3(1024), 0, stream>>>(xq8, F, slots, wxq, 0);
  k_wx_i8<<<dim3(1024), dim3(1024), 0, stream>>>(xq8, F, slots, wxq, 1);

  k_frag<<<dim3(192), dim3(256), 0, stream>>>(whh, slots, 2, F);   // R frags

  k_recur4b<<<dim3(4), dim3(1024), 0, stream>>>(wxq, F, bq, slots, h0, out,
                                                gslot);
}

// Round 5
// 14273.015 us; speedup vs baseline: 2.2082x; 1.2783x over previous
//
#include <hip/hip_runtime.h>
#include <cstdint>
#include <cstddef>

// ============================================================================
// QuantGRU on MI355X — round 7
//
// Measured so far: exchange round latency is pinned at ~1.45us (r2 structure)
// across cache-scope (r4), locality (r4), and barrier-count (r6) variations;
// 6 serial rounds/step => ~8.7us/step of sync.  The OTHER term is elementwise
// VALU: 19.2us*CU for the full domain (r5) => 4.8us/step at 4 WGs.
//
// This round: 16 WGs x 4 batch rows (16 CUs) to cut compute 4x, with the
// r2-PROVEN exchange verbatim (1 store/WG/round, tag-gated pollers, 2
// barriers, 3-ring LDS sets, parity-2 slots):
//  * GEMM row-split unchanged: 16-row MFMA tiles; ah rows 4..15 zeroed =>
//    garbage acc rows are exactly 0 (harmless under max, maxM bit-identical).
//  * Real accs live in lanes 0..15 only => scatter them through LDS (12KB)
//    so all 512 threads get 2 elementwise sites each.
//  * Per-site float op order byte-identical to r2 (absmax 0.06115723).
// ============================================================================

typedef int   v4i __attribute__((ext_vector_type(4)));
typedef float v4f __attribute__((ext_vector_type(4)));

#define T_STEPS 1024
#define OUT_MAIN_FLOATS (1024*64*256)          // 16,777,216
#define WXQ_DOUT_OFF 16842752                  // out_bytes(67,174,400) - 50,331,648
#define NWG 16

__device__ __forceinline__ float clamp128(float x) {
  return fminf(fmaxf(x, -128.0f), 127.0f);
}
__device__ __forceinline__ int permj(int j) {           // haste row -> pt row
  return j < 256 ? j + 256 : (j < 512 ? j - 256 : j);
}
__device__ __forceinline__ float sigmoidf_(float x) {
  return __fdividef(1.0f, 1.0f + __expf(-x));
}
__device__ __forceinline__ float tanhf_(float x) {
  float e = __expf(-2.0f * fabsf(x));
  float t = __fdividef(1.0f - e, 1.0f + e);
  return copysignf(t, x);
}
// monotone uint key for signed float max
__device__ __forceinline__ unsigned skey(float x) {
  unsigned u = __float_as_uint(x);
  return (u & 0x80000000u) ? ~u : (u | 0x80000000u);
}
__device__ __forceinline__ float sdec(unsigned k) {
  unsigned u = (k & 0x80000000u) ? (k ^ 0x80000000u) : ~k;
  return __uint_as_float(u);
}
__device__ __forceinline__ float wave_amax(float v) {
  #pragma unroll
  for (int m = 1; m <= 32; m <<= 1) v = fmaxf(v, __shfl_xor(v, m, 64));
  return v;
}

#define MFMA_I8(a, b, c) __builtin_amdgcn_mfma_i32_16x16x64_i8(a, b, c, 0, 0, 0)

// ---------------- absmax over a float tensor (n4 = n/4) ----------------
__global__ void k_absmax(const float* __restrict__ p, int n4, unsigned* slot) {
  int i = blockIdx.x * blockDim.x + threadIdx.x;
  int stride = gridDim.x * blockDim.x;
  const v4f* p4 = (const v4f*)p;
  float m = 0.0f;
  for (; i < n4; i += stride) {
    v4f v = p4[i];
    m = fmaxf(m, fmaxf(fmaxf(fabsf(v[0]), fabsf(v[1])),
                       fmaxf(fabsf(v[2]), fabsf(v[3]))));
  }
  m = wave_amax(m);
  if ((threadIdx.x & 63) == 0) atomicMax(slot, __float_as_uint(m));
}

// ---------------- 768x256 weight -> int8 MFMA B-fragments ----------------
__global__ void k_frag(const float* __restrict__ src,
                       const unsigned* __restrict__ slots, int slot_idx,
                       signed char* __restrict__ dst) {
  int id = blockIdx.x * 256 + threadIdx.x;   // 0..49151
  float s = fmaxf(__uint_as_float(slots[slot_idx]) / 127.0f, 1e-8f);
  int bq   = id & 3;
  int lane = (id >> 2) & 63;
  int kc   = (id >> 8) & 3;
  int ct   = id >> 10;
  int n = ct * 16 + (lane & 15);
  int k = kc * 64 + (lane >> 4) * 16 + bq * 4;
  const float* p = src + permj(n) * 256 + k;
  int b0 = ((int)clamp128(rintf(p[0] / s))) & 255;
  int b1 = ((int)clamp128(rintf(p[1] / s))) & 255;
  int b2 = ((int)clamp128(rintf(p[2] / s))) & 255;
  int b3 = ((int)clamp128(rintf(p[3] / s))) & 255;
  ((int*)dst)[id] = b0 | (b1 << 8) | (b2 << 16) | (b3 << 24);
}

// ---------------- biases: reorder + fake-quant (dequantized fp32) ----------
__global__ void k_bias(const float* __restrict__ bih, const float* __restrict__ bhh,
                       const unsigned* __restrict__ slots, float* __restrict__ bqo) {
  int j = threadIdx.x;               // 0..767
  float s_bx = fmaxf(__uint_as_float(slots[3]) / 127.0f, 1e-8f);
  float s_br = fmaxf(__uint_as_float(slots[4]) / 127.0f, 1e-8f);
  int pr = permj(j);
  bqo[j]       = s_bx * clamp128(rintf(bih[pr] / s_bx));
  bqo[768 + j] = s_br * clamp128(rintf(bhh[pr] / s_br));
}

// ---------------- quantize x -> int8 ----------------
__global__ void k_xq(const float* __restrict__ x, const unsigned* __restrict__ slots,
                     signed char* __restrict__ xq8, int n4) {
  int i = blockIdx.x * blockDim.x + threadIdx.x;
  if (i >= n4) return;
  float s_x = fmaxf(__uint_as_float(slots[0]) / 127.0f, 1e-8f);
  v4f v = ((const v4f*)x)[i];
  int b0 = ((int)clamp128(rintf(v[0] / s_x))) & 255;
  int b1 = ((int)clamp128(rintf(v[1] / s_x))) & 255;
  int b2 = ((int)clamp128(rintf(v[2] / s_x))) & 255;
  int b3 = ((int)clamp128(rintf(v[3] / s_x))) & 255;
  ((int*)xq8)[i] = b0 | (b1 << 8) | (b2 << 16) | (b3 << 24);
}

// ---------------- Wx GEMM, int8 MFMA (both passes) ----------------
__global__ __launch_bounds__(1024) void k_wx_i8(
    const signed char* __restrict__ xq8, const signed char* __restrict__ wf,
    unsigned* __restrict__ slots, signed char* __restrict__ wxq, int mode) {
  const int t = blockIdx.x;
  const int tid = threadIdx.x, lane = tid & 63, w = tid >> 6;
  const int cl = lane & 15, lh = lane >> 4;

  v4i Bz[4], Br[4], Bn[4];
  #pragma unroll
  for (int kc = 0; kc < 4; ++kc) {
    Bz[kc] = *(const v4i*)(wf + (((w)*4      + kc) * 64 + lane) * 16);
    Br[kc] = *(const v4i*)(wf + (((w + 16)*4 + kc) * 64 + lane) * 16);
    Bn[kc] = *(const v4i*)(wf + (((w + 32)*4 + kc) * 64 + lane) * 16);
  }
  v4i acc[3][4];
  #pragma unroll
  for (int p = 0; p < 3; ++p)
    #pragma unroll
    for (int rt = 0; rt < 4; ++rt) acc[p][rt] = (v4i){0, 0, 0, 0};

  const signed char* xr = xq8 + t * 16384;
  #pragma unroll
  for (int kc = 0; kc < 4; ++kc)
    #pragma unroll
    for (int rt = 0; rt < 4; ++rt) {
      v4i A = *(const v4i*)(xr + (rt * 16 + cl) * 256 + kc * 64 + lh * 16);
      acc[0][rt] = MFMA_I8(A, Bz[kc], acc[0][rt]);
      acc[1][rt] = MFMA_I8(A, Br[kc], acc[1][rt]);
      acc[2][rt] = MFMA_I8(A, Bn[kc], acc[2][rt]);
    }

  if (mode == 0) {
    int mm = 0;
    #pragma unroll
    for (int p = 0; p < 3; ++p)
      #pragma unroll
      for (int rt = 0; rt < 4; ++rt)
        #pragma unroll
        for (int rg = 0; rg < 4; ++rg) mm = max(mm, abs(acc[p][rt][rg]));
    #pragma unroll
    for (int m = 1; m <= 32; m <<= 1) mm = max(mm, __shfl_xor(mm, m, 64));
    if (lane == 0) atomicMax((int*)(slots + 5), mm);
  } else {
    int islot = *(const int*)(slots + 5);
    float maxMf = (float)islot;
    float s_x = fmaxf(__uint_as_float(slots[0]) / 127.0f, 1e-8f);
    float s_W = fmaxf(__uint_as_float(slots[1]) / 127.0f, 1e-8f);
    float s_xW = s_x * s_W;
    float s_wx = fmaxf(s_xW * maxMf / 127.0f, 1e-8f);
    #pragma unroll
    for (int p = 0; p < 3; ++p)
      #pragma unroll
      for (int rt = 0; rt < 4; ++rt) {
        int dw = 0;
        #pragma unroll
        for (int rg = 0; rg < 4; ++rg) {
          float qf = clamp128(rintf((s_xW * (float)acc[p][rt][rg]) / s_wx));
          dw |= (((int)qf) & 255) << (rg * 8);
        }
        ((int*)wxq)[t * 12288 + p * 4096 + rt * 1024 + w * 64 + lh * 16 + cl] = dw;
      }
  }
}

// ---------------- cross-WG max exchange (r2-proven structure, NWG=16) ------
// Slot = aligned 8B {tag:hi32, value:lo32}; one per (parity, wg, channel);
// per-WG slot block = 64B (own cache line).  Writers: tid<NCH publish the
// internally-reduced value once (relaxed AGENT store).  Pollers: one lane per
// remote-wg x channel spins until hi32==tag, then LDS-atomicMax the value.
// 2 barriers/round; 3-ring LDS sets; parity-2 slots; monotone tags => no ABA.
template <int NCH>
__device__ __forceinline__ void xchg(unsigned* keys, unsigned tag,
    unsigned (*lred)[8], unsigned long long* gslot, int wg, int tid, int lane) {
  const int rset = tag % 3;
  #pragma unroll
  for (int c = 0; c < NCH; ++c) {
    unsigned v = keys[c];
    #pragma unroll
    for (int m = 1; m <= 32; m <<= 1)
      v = max(v, (unsigned)__shfl_xor((int)v, m, 64));
    keys[c] = v;
  }
  if (lane == 0) {
    #pragma unroll
    for (int c = 0; c < NCH; ++c) atomicMax(&lred[rset][c], keys[c]);
  }
  __syncthreads();
  const int par = tag & 1;
  if (tid < NCH) {
    unsigned long long v =
        ((unsigned long long)tag << 32) | (unsigned long long)lred[rset][tid];
    __hip_atomic_store(&gslot[(par * NWG + wg) * 8 + tid], v,
                       __ATOMIC_RELAXED, __HIP_MEMORY_SCOPE_AGENT);
  } else if (tid == 32) {
    int ns = rset + 1; if (ns == 3) ns = 0;       // pre-zero next ring set
    #pragma unroll
    for (int c = 0; c < 8; ++c) lred[ns][c] = 0u;
  } else if (tid >= 64 && tid < 64 + (NWG - 1) * NCH) {
    int idx = tid - 64;
    int owi = idx / NCH;
    int c = idx - owi * NCH;
    int ow = owi + (owi >= wg ? 1 : 0);
    unsigned long long* p = &gslot[(par * NWG + ow) * 8 + c];
    unsigned long long v;
    do {
      v = __hip_atomic_load(p, __ATOMIC_RELAXED, __HIP_MEMORY_SCOPE_AGENT);
    } while ((unsigned)(v >> 32) != tag);
    atomicMax(&lred[rset][c], (unsigned)v);
  }
  __syncthreads();
  #pragma unroll
  for (int c = 0; c < NCH; ++c) keys[c] = lred[rset][c];
}

// ---------------- the recurrence: 16 workgroups, 4 batch rows each ---------
__global__ __launch_bounds__(512, 1) void k_recur16(
    const signed char* __restrict__ wxq, const signed char* __restrict__ brf,
    const float* __restrict__ bq, const unsigned* __restrict__ slots,
    const float* __restrict__ h0p, float* __restrict__ out,
    unsigned long long* __restrict__ gslot) {
  __shared__ signed char ah[16 * 272];     // rows 0..3 real, 4..15 zero
  __shared__ int zs[4 * 256];              // scattered acc, gate z  [row][col]
  __shared__ int rs_[4 * 256];             // gate r
  __shared__ int ns_[4 * 256];             // gate n
  __shared__ unsigned lred[3][8];          // 3-set ring x 8 channels

  const int tid = threadIdx.x;
  const int lane = tid & 63;
  const int w = tid >> 6;                  // 8 waves; wave w owns col tiles
  const int cl = lane & 15;                //   {2w,2w+1} x 3 gates
  const int lh = lane >> 4;
  const int wg = blockIdx.x;               // 0..15 -> batch rows 4*wg..+3
  const int j = tid & 255;                 // elementwise column 0..255
  const int rp = (tid >> 8) * 2;           // elementwise row pair {rp, rp+1}

  // zero lred + whole ah (rows 4..15 stay zero forever)
  if (tid < 24) ((unsigned*)lred)[tid] = 0u;
  for (int i = tid; i < 1088; i += 512) ((int*)ah)[i] = 0;

  float s_x = fmaxf(__uint_as_float(slots[0]) / 127.0f, 1e-8f);
  float s_W = fmaxf(__uint_as_float(slots[1]) / 127.0f, 1e-8f);
  float s_R = fmaxf(__uint_as_float(slots[2]) / 127.0f, 1e-8f);
  float maxM0 = (float)(*(const int*)(slots + 5));
  float s_wx = fmaxf(s_x * s_W * maxM0 / 127.0f, 1e-8f);

  float bxz = bq[j], bxr = bq[j + 256], bxn = bq[j + 512];
  float brz = bq[768 + j], brr = bq[1024 + j], brn = bq[1280 + j];

  // R fragments, resident: 2 col-tiles x 3 gates x 4 kc
  v4i Bz[2][4], Br[2][4], Bn[2][4];
  #pragma unroll
  for (int cg = 0; cg < 2; ++cg) {
    int ct = w * 2 + cg;
    #pragma unroll
    for (int kc = 0; kc < 4; ++kc) {
      Bz[cg][kc] = *(const v4i*)(brf + ((ct * 4        + kc) * 64 + lane) * 16);
      Br[cg][kc] = *(const v4i*)(brf + (((ct + 16) * 4 + kc) * 64 + lane) * 16);
      Bn[cg][kc] = *(const v4i*)(brf + (((ct + 32) * 4 + kc) * 64 + lane) * 16);
    }
  }

  float h[2];
  #pragma unroll
  for (int s = 0; s < 2; ++s)
    h[s] = h0p[(wg * 4 + rp + s) * 256 + j];

  __syncthreads();                         // lred + ah zeros visible

  unsigned tag = 1;
  float sh;
  {
    float m = fmaxf(fabsf(h[0]), fabsf(h[1]));
    unsigned kk[1] = {__float_as_uint(m)};
    xchg<1>(kk, tag++, lred, gslot, wg, tid, lane);
    sh = fmaxf(__uint_as_float(kk[0]) / 127.0f, 1e-8f);
    float ish = 1.0f / sh;
    #pragma unroll
    for (int s = 0; s < 2; ++s)
      ah[(rp + s) * 272 + j] = (signed char)(int)rintf(h[s] * ish);
    __syncthreads();
  }

  const int widx0 = (wg >> 2) * 1024 + (j >> 4) * 64 + (wg & 3) * 16 + (j & 15);

  for (int t = 0; t < T_STEPS; ++t) {
    // Wx code dwords: one dword covers both sites (bytes rp, rp+1)
    const int* wxi = (const int*)wxq + (size_t)t * 12288 + widx0;
    int wvz = wxi[0];
    int wvr = wxi[4096];
    int wvn = wxi[8192];

    // ---- GEMM: rows 0..3 real (rows 4..15 of ah are zero) ----
    v4i aZ[2] = {(v4i){0,0,0,0}, (v4i){0,0,0,0}};
    v4i aR[2] = {(v4i){0,0,0,0}, (v4i){0,0,0,0}};
    v4i aN[2] = {(v4i){0,0,0,0}, (v4i){0,0,0,0}};
    #pragma unroll
    for (int kc = 0; kc < 4; ++kc) {
      v4i A = *(const v4i*)(ah + cl * 272 + kc * 64 + lh * 16);
      #pragma unroll
      for (int cg = 0; cg < 2; ++cg) {
        aZ[cg] = MFMA_I8(A, Bz[cg][kc], aZ[cg]);
        aR[cg] = MFMA_I8(A, Br[cg][kc], aR[cg]);
        aN[cg] = MFMA_I8(A, Bn[cg][kc], aN[cg]);
      }
    }

    // scatter real accs (lanes 0..15 hold rows 0..3) into LDS; the R1
    // round's barriers order these writes before the reads below.
    if (lane < 16) {
      #pragma unroll
      for (int cg = 0; cg < 2; ++cg) {
        int jj = (w * 2 + cg) * 16 + lane;
        #pragma unroll
        for (int rg = 0; rg < 4; ++rg) {
          zs[rg * 256 + jj] = aZ[cg][rg];
          rs_[rg * 256 + jj] = aR[cg][rg];
          ns_[rg * 256 + jj] = aN[cg][rg];
        }
      }
    }

    // ---- R1: global max|acc| (garbage rows contribute exactly 0) ----
    int mm = 0;
    #pragma unroll
    for (int cg = 0; cg < 2; ++cg)
      #pragma unroll
      for (int rg = 0; rg < 4; ++rg)
        mm = max(mm, max(abs(aZ[cg][rg]),
                         max(abs(aR[cg][rg]), abs(aN[cg][rg]))));
    unsigned kk[5];
    kk[0] = (unsigned)mm;
    xchg<1>(kk, tag++, lred, gslot, wg, tid, lane);
    float maxMf = (float)(int)kk[0];
    float s_Rh = fmaxf(sh * s_R * maxMf / 127.0f, 1e-8f);
    float fRh = (sh * s_R) / s_Rh;

    // ---- stage B: z_pre, r_pre, Rh_n+br_n + abs/signed maxes ----
    float zp[2], rpre[2], nb[2];
    float az = 0.0f, ar = 0.0f, an = 0.0f;
    float mzs = -3.402823466e38f, mrs = -3.402823466e38f;
    #pragma unroll
    for (int s = 0; s < 2; ++s) {
      int r = rp + s;
      float Rz = s_Rh * rintf((float)zs[r * 256 + j] * fRh);
      float Rr = s_Rh * rintf((float)rs_[r * 256 + j] * fRh);
      float Rn = s_Rh * rintf((float)ns_[r * 256 + j] * fRh);
      float wz = s_wx * (float)((signed char)(wvz >> (r * 8)));
      float wr = s_wx * (float)((signed char)(wvr >> (r * 8)));
      float a1 = ((wz + bxz) + Rz) + brz;
      float a2 = ((wr + bxr) + Rr) + brr;
      float a3 = Rn + brn;
      zp[s] = a1; rpre[s] = a2; nb[s] = a3;
      az = fmaxf(az, fabsf(a1)); ar = fmaxf(ar, fabsf(a2));
      an = fmaxf(an, fabsf(a3));
      mzs = fmaxf(mzs, a1); mrs = fmaxf(mrs, a2);
    }
    kk[0] = __float_as_uint(az); kk[1] = __float_as_uint(ar);
    kk[2] = __float_as_uint(an); kk[3] = skey(mzs); kk[4] = skey(mrs);
    xchg<5>(kk, tag++, lred, gslot, wg, tid, lane);
    float s1 = fmaxf(__uint_as_float(kk[0]) / 127.0f, 1e-8f), i1 = 1.0f / s1;
    float s2 = fmaxf(__uint_as_float(kk[1]) / 127.0f, 1e-8f), i2 = 1.0f / s2;
    float s3 = fmaxf(__uint_as_float(kk[2]) / 127.0f, 1e-8f), i3 = 1.0f / s3;
    float zq_max = s1 * rintf(sdec(kk[3]) * i1);
    float rq_max = s2 * rintf(sdec(kk[4]) * i2);
    float s4 = fmaxf(sigmoidf_(zq_max) / 127.0f, 1e-8f), i4 = 1.0f / s4;
    float s5 = fmaxf(sigmoidf_(rq_max) / 127.0f, 1e-8f), i5 = 1.0f / s5;

    // ---- stage C: z final, rRh ----
    float zf[2], rr_[2];
    float m6 = 0.0f;
    #pragma unroll
    for (int s = 0; s < 2; ++s) {
      float zq = s1 * rintf(zp[s] * i1);
      float rq = s2 * rintf(rpre[s] * i2);
      float zv = sigmoidf_(zq);
      float rv = sigmoidf_(rq);
      zf[s] = s4 * rintf(zv * i4);
      float rq2 = s5 * rintf(rv * i5);
      float nbq = s3 * rintf(nb[s] * i3);
      float rr = rq2 * nbq;
      rr_[s] = rr;
      m6 = fmaxf(m6, fabsf(rr));
    }
    kk[0] = __float_as_uint(m6);
    xchg<1>(kk, tag++, lred, gslot, wg, tid, lane);
    float s6 = fmaxf(__uint_as_float(kk[0]) / 127.0f, 1e-8f), i6 = 1.0f / s6;

    // ---- stage D: g_pre ----
    float gp[2];
    float m7 = 0.0f;
    #pragma unroll
    for (int s = 0; s < 2; ++s) {
      float rrq = s6 * rintf(rr_[s] * i6);
      float wn = s_wx * (float)((signed char)(wvn >> ((rp + s) * 8)));
      float g = (wn + bxn) + rrq;
      gp[s] = g;
      m7 = fmaxf(m7, fabsf(g));
    }
    kk[0] = __float_as_uint(m7);
    xchg<1>(kk, tag++, lred, gslot, wg, tid, lane);
    float m7g = __uint_as_float(kk[0]);
    float s7 = fmaxf(m7g / 127.0f, 1e-8f), i7 = 1.0f / s7;
    float gq_max = s7 * rintf(m7g * i7);
    float s8 = fmaxf(tanhf_(gq_max) / 127.0f, 1e-8f), i8v = 1.0f / s8;

    // ---- stage E: g, old/new contribs ----
    float ov[2], nv[2];
    float mo = 0.0f, mn = 0.0f;
    #pragma unroll
    for (int s = 0; s < 2; ++s) {
      float gpq = s7 * rintf(gp[s] * i7);
      float gv = tanhf_(gpq);
      float gq = s8 * rintf(gv * i8v);
      float o = zf[s] * h[s];
      float n = (1.0f - zf[s]) * gq;
      ov[s] = o; nv[s] = n;
      mo = fmaxf(mo, fabsf(o)); mn = fmaxf(mn, fabsf(n));
    }
    kk[0] = __float_as_uint(mo); kk[1] = __float_as_uint(mn);
    xchg<2>(kk, tag++, lred, gslot, wg, tid, lane);
    float s9  = fmaxf(__uint_as_float(kk[0]) / 127.0f, 1e-8f), i9  = 1.0f / s9;
    float s10 = fmaxf(__uint_as_float(kk[1]) / 127.0f, 1e-8f), i10 = 1.0f / s10;

    // ---- stage F: h_new, write output ----
    float mh = 0.0f;
    #pragma unroll
    for (int s = 0; s < 2; ++s) {
      float oq = s9  * rintf(ov[s] * i9);
      float nq = s10 * rintf(nv[s] * i10);
      float hn = oq + nq;
      h[s] = hn;
      mh = fmaxf(mh, fabsf(hn));
      out[t * 16384 + (wg * 4 + rp + s) * 256 + j] = hn;
    }
    kk[0] = __float_as_uint(mh);
    xchg<1>(kk, tag++, lred, gslot, wg, tid, lane);
    sh = fmaxf(__uint_as_float(kk[0]) / 127.0f, 1e-8f);
    float ish = 1.0f / sh;
    #pragma unroll
    for (int s = 0; s < 2; ++s)
      ah[(rp + s) * 272 + j] = (signed char)(int)rintf(h[s] * ish);
    __syncthreads();                       // ah ready for next step
  }

  // h_last
  #pragma unroll
  for (int s = 0; s < 2; ++s)
    out[OUT_MAIN_FLOATS + (wg * 4 + rp + s) * 256 + j] = h[s];
}

// ============================================================================
extern "C" void kernel_launch(void* const* d_in, const int* in_sizes, int n_in,
                              void* d_out, int out_size, void* d_ws, size_t ws_size,
                              hipStream_t stream) {
  const float* x   = (const float*)d_in[0];   // (1024,64,256)
  const float* wih = (const float*)d_in[1];   // (768,256)
  const float* whh = (const float*)d_in[2];   // (768,256)
  const float* bih = (const float*)d_in[3];   // (768,)
  const float* bhh = (const float*)d_in[4];   // (768,)
  const float* h0  = (const float*)d_in[5];   // (64,256)
  float* out = (float*)d_out;

  // d_ws layout: [0..255] absmax slots; [512..2559] tagged exchange slots
  // (2 parity x 16 wg x 8 ch x 8B = 2048B, 64B line per WG); [4096..] bq;
  // [10240..] fragment buffer F (196,608B).
  unsigned* slots = (unsigned*)d_ws;
  unsigned long long* gslot = (unsigned long long*)((char*)d_ws + 512);
  float* bq       = (float*)((char*)d_ws + 4096);
  signed char* F  = (signed char*)d_ws + 10240;

  signed char* wxq = (signed char*)d_out + WXQ_DOUT_OFF; // tail of d_out
  signed char* xq8 = (signed char*)d_out;                // head (dead later)

  hipMemsetAsync(d_ws, 0, 4096, stream);

  k_absmax<<<dim3(1024), dim3(256), 0, stream>>>(x,   16777216 / 4, slots + 0);
  k_absmax<<<dim3(96),   dim3(256), 0, stream>>>(wih, 196608 / 4,   slots + 1);
  k_absmax<<<dim3(96),   dim3(256), 0, stream>>>(whh, 196608 / 4,   slots + 2);
  k_absmax<<<dim3(1),    dim3(256), 0, stream>>>(bih, 768 / 4,      slots + 3);
  k_absmax<<<dim3(1),    dim3(256), 0, stream>>>(bhh, 768 / 4,      slots + 4);

  k_frag<<<dim3(192), dim3(256), 0, stream>>>(wih, slots, 1, F);   // W frags
  k_bias<<<dim3(1), dim3(768), 0, stream>>>(bih, bhh, slots, bq);
  k_xq<<<dim3(16384), dim3(256), 0, stream>>>(x, slots, xq8, 4194304);

  k_wx_i8<<<dim3(1024), dim3(1024), 0, stream>>>(xq8, F, slots, wxq, 0);
  k_wx_i8<<<dim3(1024), dim3(1024), 0, stream>>>(xq8, F, slots, wxq, 1);

  k_frag<<<dim3(192), dim3(256), 0, stream>>>(whh, slots, 2, F);   // R frags

  k_recur16<<<dim3(NWG), dim3(512), 0, stream>>>(wxq, F, bq, slots, h0, out,
                                                 gslot);
}